// Round 3
// baseline (147.220 us; speedup 1.0000x reference)
//
#include <hip/hip_runtime.h>

// ---------------- problem constants ----------------
#define NS 32768
// output flat offsets (fp32 elements)
#define OUT1_BASE (NS * 256)                 // 8388608
#define OUT2_BASE (OUT1_BASE + NS * 576)     // 27262976
#define OUT3_BASE (OUT2_BASE + NS * 640)     // 48234496

typedef float f4 __attribute__((ext_vector_type(4)));

// ================= compile-time U construction =================
namespace cgc {

constexpr double hfact(int n) { double r = 1.0; for (int i = 2; i <= n; ++i) r *= (double)i; return r; }

constexpr double csqrt(double a) {
    if (a <= 0.0) return 0.0;
    double x = a > 1.0 ? a : 1.0;
    for (int i = 0; i < 64; ++i) x = 0.5 * (x + a / x);
    return x;
}

constexpr double cg_coeff(int j1, int m1, int j2, int m2, int J, int M) {
    if (m1 + m2 != M) return 0.0;
    double pref = (2.0 * J + 1.0) * hfact(j1 + j2 - J) * hfact(j1 - j2 + J)
                * hfact(-j1 + j2 + J) / hfact(j1 + j2 + J + 1);
    pref *= hfact(J + M) * hfact(J - M) * hfact(j1 - m1) * hfact(j1 + m1)
          * hfact(j2 - m2) * hfact(j2 + m2);
    int kmin = 0;
    if (j2 - J - m1 > kmin) kmin = j2 - J - m1;
    if (j1 + m2 - J > kmin) kmin = j1 + m2 - J;
    int kmax = j1 + j2 - J;
    if (j1 - m1 < kmax) kmax = j1 - m1;
    if (j2 + m2 < kmax) kmax = j2 + m2;
    double s = 0.0;
    for (int k = kmin; k <= kmax; ++k) {
        double d = hfact(k) * hfact(j1 + j2 - J - k) * hfact(j1 - m1 - k)
                 * hfact(j2 + m2 - k) * hfact(J - j2 + m1 + k) * hfact(J - j1 - m2 + k);
        s += ((k & 1) ? -1.0 : 1.0) / d;
    }
    return csqrt(pref) * s;
}

struct C2 { double re; double im; };
constexpr C2 cmul(C2 a, C2 b) { return { a.re * b.re - a.im * b.im, a.re * b.im + a.im * b.re }; }
constexpr C2 cadd(C2 a, C2 b) { return { a.re + b.re, a.im + b.im }; }
constexpr C2 cscale(C2 a, double s) { return { a.re * s, a.im * s }; }
constexpr C2 conjc(C2 a) { return { a.re, -a.im }; }

struct R2C { C2 r[81]; };

constexpr R2C real2complex(int L) {
    R2C R{};
    int D = 2 * L + 1;
    double isq2 = 1.0 / csqrt(2.0);
    for (int m = -L; m <= L; ++m) {
        double sgn = (m & 1) ? -1.0 : 1.0;
        if (m < 0) {
            R.r[(L - m) * D + (L + m)] = { 0.0, isq2 * sgn };
            R.r[(L + m) * D + (L + m)] = { 0.0, -isq2 };
        } else if (m == 0) {
            R.r[L * D + L] = { 1.0, 0.0 };
        } else {
            R.r[(L - m) * D + (L + m)] = { isq2, 0.0 };
            R.r[(L + m) * D + (L + m)] = { isq2 * sgn, 0.0 };
        }
    }
    return R;
}

struct Blk { double v[225]; };

constexpr Blk cg_real(int l1, int l2, int L) {
    Blk out{};
    int D1 = 2 * l1 + 1, D2 = 2 * l2 + 1, DL = 2 * L + 1;
    double ccg[225] = {};
    for (int m1 = -l1; m1 <= l1; ++m1)
        for (int m2 = -l2; m2 <= l2; ++m2) {
            int M = m1 + m2;
            if (M >= -L && M <= L)
                ccg[((m1 + l1) * D2 + (m2 + l2)) * DL + (M + L)] = cg_coeff(l1, m1, l2, m2, L, M);
        }
    R2C R1 = real2complex(l1);
    R2C R2 = real2complex(l2);
    R2C RL = real2complex(L);
    bool even = ((l1 + l2 + L) % 2) == 0;
    for (int a = 0; a < D1; ++a)
        for (int b = 0; b < D2; ++b) {
            C2 tmp[9] = {};
            for (int M = 0; M < DL; ++M) {
                C2 s = { 0.0, 0.0 };
                for (int m = 0; m < D1; ++m)
                    for (int nn = 0; nn < D2; ++nn) {
                        double cc = ccg[(m * D2 + nn) * DL + M];
                        if (cc != 0.0)
                            s = cadd(s, cscale(cmul(R1.r[m * D1 + a], R2.r[nn * D2 + b]), cc));
                    }
                tmp[M] = s;
            }
            for (int k = 0; k < DL; ++k) {
                C2 s = { 0.0, 0.0 };
                for (int M = 0; M < DL; ++M)
                    s = cadd(s, cmul(tmp[M], conjc(RL.r[M * DL + k])));
                out.v[(a * D2 + b) * DL + k] = even ? s.re : s.im;
            }
        }
    return out;
}

constexpr Blk B2_0 = cg_real(1, 1, 0);
constexpr Blk B2_1 = cg_real(1, 1, 1);
constexpr Blk B2_2 = cg_real(1, 1, 2);
constexpr Blk B4_0 = cg_real(2, 2, 0);
constexpr Blk B4_1 = cg_real(2, 2, 1);
constexpr Blk B4_2 = cg_real(2, 2, 2);
constexpr Blk B4_3 = cg_real(2, 2, 3);
constexpr Blk B4_4 = cg_real(2, 2, 4);

struct U9T  { float u[81];  };
struct U25T { float u[625]; };

constexpr U9T build_U9() {
    U9T U{};
    const Blk* bl[3] = { &B2_0, &B2_1, &B2_2 };
    int off = 0;
    for (int L = 0; L <= 2; ++L) {
        int DL = 2 * L + 1;
        for (int a = 0; a < 3; ++a)
            for (int b = 0; b < 3; ++b)
                for (int k = 0; k < DL; ++k)
                    U.u[(a * 3 + b) * 9 + (off + k)] = (float)bl[L]->v[(a * 3 + b) * DL + k];
        off += DL;
    }
    return U;
}

constexpr U25T build_U25() {
    U25T U{};
    const Blk* bl[5] = { &B4_0, &B4_1, &B4_2, &B4_3, &B4_4 };
    int off = 0;
    for (int L = 0; L <= 4; ++L) {
        int DL = 2 * L + 1;
        for (int a = 0; a < 5; ++a)
            for (int b = 0; b < 5; ++b)
                for (int k = 0; k < DL; ++k)
                    U.u[(a * 5 + b) * 25 + (off + k)] = (float)bl[L]->v[(a * 5 + b) * DL + k];
        off += DL;
    }
    return U;
}

constexpr U9T  U9c  = build_U9();
constexpr U25T U25c = build_U25();

} // namespace cgc

// ================= LDS-staged fused kernel =================
// Block = 256 threads = 4 samples x 64 channels.
// Phase 1: cooperative dwordx4 copy of all input slices for 4 samples to LDS.
// Phase 2: per-(sample,channel) scalar compute from LDS into registers.
// Phase 3: y -> LDS (overlaying consumed inputs) -> dwordx4 NT stores.

// LDS offsets in float4 units (per block, 4 samples)
#define L4_F1_0 0      // 256 f4
#define L4_F1_1 256    // 576 f4
#define L4_F1_2 832    // 640 f4
#define L4_F1_3 1472   // 448 f4
#define L4_F2_0 1920
#define L4_F2_1 2176
#define L4_F2_2 2752
#define L4_F2_3 3392
#define L4_TOT  3840   // 61440 bytes
// float-unit views
#define LF_F1_0 0
#define LF_F1_1 1024
#define LF_F1_2 3328
#define LF_F1_3 5888
#define LF_F2_0 7680
#define LF_F2_1 8704
#define LF_F2_2 11008
#define LF_F2_3 13568
// output overlay (floats / f4)
#define LF_O0 0
#define LF_O1 1024
#define LF_O2 3328
#define LF_O3 5888
#define L4_O0 0
#define L4_O1 256
#define L4_O2 832
#define L4_O3 1472

__global__ __launch_bounds__(256) void tp_lds_kernel(
    const float* __restrict__ f1_0, const float* __restrict__ f1_1,
    const float* __restrict__ f1_2, const float* __restrict__ f1_3,
    const float* __restrict__ f2_0, const float* __restrict__ f2_1,
    const float* __restrict__ f2_2, const float* __restrict__ f2_3,
    float* __restrict__ out)
{
    using namespace cgc;
    __shared__ f4 lds4[L4_TOT];
    float* lds = (float*)lds4;

    const int tid = threadIdx.x;
    const int n0 = blockIdx.x * 4;

    // ---------------- phase 1: global -> LDS (float4) ----------------
    {
        const f4* g10 = (const f4*)f1_0 + n0 * 64;
        const f4* g11 = (const f4*)f1_1 + n0 * 144;
        const f4* g12 = (const f4*)f1_2 + n0 * 160;
        const f4* g13 = (const f4*)f1_3 + n0 * 112;
        const f4* g20 = (const f4*)f2_0 + n0 * 64;
        const f4* g21 = (const f4*)f2_1 + n0 * 144;
        const f4* g22 = (const f4*)f2_2 + n0 * 160;
        const f4* g23 = (const f4*)f2_3 + n0 * 112;

        // full rounds (independent, deep ILP)
        lds4[L4_F1_0 + tid]       = g10[tid];
        lds4[L4_F1_1 + tid]       = g11[tid];
        lds4[L4_F1_1 + 256 + tid] = g11[256 + tid];
        lds4[L4_F1_2 + tid]       = g12[tid];
        lds4[L4_F1_2 + 256 + tid] = g12[256 + tid];
        lds4[L4_F1_3 + tid]       = g13[tid];
        lds4[L4_F2_0 + tid]       = g20[tid];
        lds4[L4_F2_1 + tid]       = g21[tid];
        lds4[L4_F2_1 + 256 + tid] = g21[256 + tid];
        lds4[L4_F2_2 + tid]       = g22[tid];
        lds4[L4_F2_2 + 256 + tid] = g22[256 + tid];
        lds4[L4_F2_3 + tid]       = g23[tid];
        // partial rounds
        if (tid < 64) {
            lds4[L4_F1_1 + 512 + tid] = g11[512 + tid];
            lds4[L4_F2_1 + 512 + tid] = g21[512 + tid];
        }
        if (tid < 128) {
            lds4[L4_F1_2 + 512 + tid] = g12[512 + tid];
            lds4[L4_F2_2 + 512 + tid] = g22[512 + tid];
        }
        if (tid < 192) {
            lds4[L4_F1_3 + 256 + tid] = g13[256 + tid];
            lds4[L4_F2_3 + 256 + tid] = g23[256 + tid];
        }
    }
    __syncthreads();

    // ---------------- phase 2: compute (LDS -> registers) ----------------
    const int s = tid >> 6, c = tid & 63;
    const int b0 = s * 256, b1 = s * 576, b2 = s * 640, b3 = s * 448;

    float y0;                 // band0 -> out0 ch c
    float y1[4];              // band1 -> out0 ch 64+c, out1 ch c
    float y2[9];              // band2 -> out0 ch 128+c, out1 ch 64+c, out2 ch c
    float y3[16];             // band3 -> out0 ch 192+c, out1 ch 128+c, out2 ch 64+c, out3 ch c

    // band 0
    y0 = lds[LF_F1_0 + b0 + 192 + c] * lds[LF_F2_0 + b0 + 192 + c];

    // band 1 (pl=2, 4 of 9 inputs, outputs L=0,1)
    {
        const int ch = 128 + c;
        float x1[4], x2[4];
        x1[0] = lds[LF_F1_0 + b0 + ch];
        x2[0] = lds[LF_F2_0 + b0 + ch];
#pragma unroll
        for (int m = 0; m < 3; ++m) {
            x1[1 + m] = lds[LF_F1_1 + b1 + m * 192 + ch];
            x2[1 + m] = lds[LF_F2_1 + b1 + m * 192 + ch];
        }
        float A[9], B[9];
#pragma unroll
        for (int M = 0; M < 9; ++M) {
            float sa = 0.f, sb = 0.f;
#pragma unroll
            for (int N = 0; N < 4; ++N)
                if (U9c.u[M * 9 + N] != 0.0f) {
                    sa += U9c.u[M * 9 + N] * x1[N];
                    sb += U9c.u[M * 9 + N] * x2[N];
                }
            A[M] = sa; B[M] = sb;
        }
        float C[9];
#pragma unroll
        for (int i = 0; i < 3; ++i)
#pragma unroll
            for (int k = 0; k < 3; ++k) {
                float sC = 0.f;
#pragma unroll
                for (int j = 0; j < 3; ++j) sC += A[i * 3 + j] * B[j * 3 + k];
                C[i * 3 + k] = sC;
            }
#pragma unroll
        for (int M = 0; M < 4; ++M) {
            float sY = 0.f;
#pragma unroll
            for (int N = 0; N < 9; ++N)
                if (U9c.u[N * 9 + M] != 0.0f) sY += U9c.u[N * 9 + M] * C[N];
            y1[M] = sY;
        }
    }

    // band 2 (pl=2, all 9 inputs, outputs L=0..2)
    {
        const int ch = 64 + c;
        float x1[9], x2[9];
        x1[0] = lds[LF_F1_0 + b0 + ch];
        x2[0] = lds[LF_F2_0 + b0 + ch];
#pragma unroll
        for (int m = 0; m < 3; ++m) {
            x1[1 + m] = lds[LF_F1_1 + b1 + m * 192 + ch];
            x2[1 + m] = lds[LF_F2_1 + b1 + m * 192 + ch];
        }
#pragma unroll
        for (int m = 0; m < 5; ++m) {
            x1[4 + m] = lds[LF_F1_2 + b2 + m * 128 + ch];
            x2[4 + m] = lds[LF_F2_2 + b2 + m * 128 + ch];
        }
        float A[9], B[9];
#pragma unroll
        for (int M = 0; M < 9; ++M) {
            float sa = 0.f, sb = 0.f;
#pragma unroll
            for (int N = 0; N < 9; ++N)
                if (U9c.u[M * 9 + N] != 0.0f) {
                    sa += U9c.u[M * 9 + N] * x1[N];
                    sb += U9c.u[M * 9 + N] * x2[N];
                }
            A[M] = sa; B[M] = sb;
        }
        float C[9];
#pragma unroll
        for (int i = 0; i < 3; ++i)
#pragma unroll
            for (int k = 0; k < 3; ++k) {
                float sC = 0.f;
#pragma unroll
                for (int j = 0; j < 3; ++j) sC += A[i * 3 + j] * B[j * 3 + k];
                C[i * 3 + k] = sC;
            }
#pragma unroll
        for (int M = 0; M < 9; ++M) {
            float sY = 0.f;
#pragma unroll
            for (int N = 0; N < 9; ++N)
                if (U9c.u[N * 9 + M] != 0.0f) sY += U9c.u[N * 9 + M] * C[N];
            y2[M] = sY;
        }
    }

    // band 3 (pl=4, 16 of 25 inputs, outputs L=0..3)
    {
        float x1[16], x2[16];
        x1[0] = lds[LF_F1_0 + b0 + c];
        x2[0] = lds[LF_F2_0 + b0 + c];
#pragma unroll
        for (int m = 0; m < 3; ++m) {
            x1[1 + m] = lds[LF_F1_1 + b1 + m * 192 + c];
            x2[1 + m] = lds[LF_F2_1 + b1 + m * 192 + c];
        }
#pragma unroll
        for (int m = 0; m < 5; ++m) {
            x1[4 + m] = lds[LF_F1_2 + b2 + m * 128 + c];
            x2[4 + m] = lds[LF_F2_2 + b2 + m * 128 + c];
        }
#pragma unroll
        for (int m = 0; m < 7; ++m) {
            x1[9 + m] = lds[LF_F1_3 + b3 + m * 64 + c];
            x2[9 + m] = lds[LF_F2_3 + b3 + m * 64 + c];
        }
        float A[25], B[25];
#pragma unroll
        for (int M = 0; M < 25; ++M) {
            float sa = 0.f, sb = 0.f;
#pragma unroll
            for (int N = 0; N < 16; ++N)
                if (U25c.u[M * 25 + N] != 0.0f) {
                    sa += U25c.u[M * 25 + N] * x1[N];
                    sb += U25c.u[M * 25 + N] * x2[N];
                }
            A[M] = sa; B[M] = sb;
        }
        float C[25];
#pragma unroll
        for (int i = 0; i < 5; ++i)
#pragma unroll
            for (int k = 0; k < 5; ++k) {
                float sC = 0.f;
#pragma unroll
                for (int j = 0; j < 5; ++j) sC += A[i * 5 + j] * B[j * 5 + k];
                C[i * 5 + k] = sC;
            }
#pragma unroll
        for (int M = 0; M < 16; ++M) {
            float sY = 0.f;
#pragma unroll
            for (int N = 0; N < 25; ++N)
                if (U25c.u[N * 25 + M] != 0.0f) sY += U25c.u[N * 25 + M] * C[N];
            y3[M] = sY;
        }
    }

    // all LDS input reads complete before overlay writes
    __syncthreads();

    // ---------------- phase 2b: y -> LDS (output overlay) ----------------
    lds[LF_O0 + b0 + c]        = y0;
    lds[LF_O0 + b0 + 64 + c]   = y1[0];
    lds[LF_O0 + b0 + 128 + c]  = y2[0];
    lds[LF_O0 + b0 + 192 + c]  = y3[0];
#pragma unroll
    for (int m = 0; m < 3; ++m) {
        lds[LF_O1 + b1 + m * 192 + c]        = y1[1 + m];
        lds[LF_O1 + b1 + m * 192 + 64 + c]   = y2[1 + m];
        lds[LF_O1 + b1 + m * 192 + 128 + c]  = y3[1 + m];
    }
#pragma unroll
    for (int m = 0; m < 5; ++m) {
        lds[LF_O2 + b2 + m * 128 + c]       = y2[4 + m];
        lds[LF_O2 + b2 + m * 128 + 64 + c]  = y3[4 + m];
    }
#pragma unroll
    for (int m = 0; m < 7; ++m)
        lds[LF_O3 + b3 + m * 64 + c] = y3[9 + m];

    __syncthreads();

    // ---------------- phase 3: LDS -> global (float4, nontemporal) ----------------
    {
        f4* o0 = (f4*)out + n0 * 64;
        f4* o1 = (f4*)out + 2097152 + n0 * 144;   // OUT1_BASE/4
        f4* o2 = (f4*)out + 6815744 + n0 * 160;   // OUT2_BASE/4
        f4* o3 = (f4*)out + 12058624 + n0 * 112;  // OUT3_BASE/4

        __builtin_nontemporal_store(lds4[L4_O0 + tid],       &o0[tid]);
        __builtin_nontemporal_store(lds4[L4_O1 + tid],       &o1[tid]);
        __builtin_nontemporal_store(lds4[L4_O1 + 256 + tid], &o1[256 + tid]);
        __builtin_nontemporal_store(lds4[L4_O2 + tid],       &o2[tid]);
        __builtin_nontemporal_store(lds4[L4_O2 + 256 + tid], &o2[256 + tid]);
        __builtin_nontemporal_store(lds4[L4_O3 + tid],       &o3[tid]);
        if (tid < 64)
            __builtin_nontemporal_store(lds4[L4_O1 + 512 + tid], &o1[512 + tid]);
        if (tid < 128)
            __builtin_nontemporal_store(lds4[L4_O2 + 512 + tid], &o2[512 + tid]);
        if (tid < 192)
            __builtin_nontemporal_store(lds4[L4_O3 + 256 + tid], &o3[256 + tid]);
    }
}

// ---------------- launch ----------------
extern "C" void kernel_launch(void* const* d_in, const int* in_sizes, int n_in,
                              void* d_out, int out_size, void* d_ws, size_t ws_size,
                              hipStream_t stream)
{
    const float* f1_0 = (const float*)d_in[0];
    const float* f1_1 = (const float*)d_in[1];
    const float* f1_2 = (const float*)d_in[2];
    const float* f1_3 = (const float*)d_in[3];
    const float* f2_0 = (const float*)d_in[4];
    const float* f2_1 = (const float*)d_in[5];
    const float* f2_2 = (const float*)d_in[6];
    const float* f2_3 = (const float*)d_in[7];
    float* out = (float*)d_out;

    dim3 blk(256);
    dim3 grid(NS / 4);   // 4 samples per block

    tp_lds_kernel<<<grid, blk, 0, stream>>>(f1_0, f1_1, f1_2, f1_3,
                                            f2_0, f2_1, f2_2, f2_3, out);
}

// Round 4
// 138.585 us; speedup vs baseline: 1.0623x; 1.0623x over previous
//
#include <hip/hip_runtime.h>

// ---------------- problem constants ----------------
#define NS 32768
// output flat offsets (fp32 elements)
#define OUT1_BASE (NS * 256)                 // 8388608
#define OUT2_BASE (OUT1_BASE + NS * 576)     // 27262976
#define OUT3_BASE (OUT2_BASE + NS * 640)     // 48234496

// ================= compile-time U construction =================
namespace cgc {

constexpr double hfact(int n) { double r = 1.0; for (int i = 2; i <= n; ++i) r *= (double)i; return r; }

constexpr double csqrt(double a) {
    if (a <= 0.0) return 0.0;
    double x = a > 1.0 ? a : 1.0;
    for (int i = 0; i < 64; ++i) x = 0.5 * (x + a / x);
    return x;
}

constexpr double cg_coeff(int j1, int m1, int j2, int m2, int J, int M) {
    if (m1 + m2 != M) return 0.0;
    double pref = (2.0 * J + 1.0) * hfact(j1 + j2 - J) * hfact(j1 - j2 + J)
                * hfact(-j1 + j2 + J) / hfact(j1 + j2 + J + 1);
    pref *= hfact(J + M) * hfact(J - M) * hfact(j1 - m1) * hfact(j1 + m1)
          * hfact(j2 - m2) * hfact(j2 + m2);
    int kmin = 0;
    if (j2 - J - m1 > kmin) kmin = j2 - J - m1;
    if (j1 + m2 - J > kmin) kmin = j1 + m2 - J;
    int kmax = j1 + j2 - J;
    if (j1 - m1 < kmax) kmax = j1 - m1;
    if (j2 + m2 < kmax) kmax = j2 + m2;
    double s = 0.0;
    for (int k = kmin; k <= kmax; ++k) {
        double d = hfact(k) * hfact(j1 + j2 - J - k) * hfact(j1 - m1 - k)
                 * hfact(j2 + m2 - k) * hfact(J - j2 + m1 + k) * hfact(J - j1 - m2 + k);
        s += ((k & 1) ? -1.0 : 1.0) / d;
    }
    return csqrt(pref) * s;
}

struct C2 { double re; double im; };
constexpr C2 cmul(C2 a, C2 b) { return { a.re * b.re - a.im * b.im, a.re * b.im + a.im * b.re }; }
constexpr C2 cadd(C2 a, C2 b) { return { a.re + b.re, a.im + b.im }; }
constexpr C2 cscale(C2 a, double s) { return { a.re * s, a.im * s }; }
constexpr C2 conjc(C2 a) { return { a.re, -a.im }; }

struct R2C { C2 r[81]; };

constexpr R2C real2complex(int L) {
    R2C R{};
    int D = 2 * L + 1;
    double isq2 = 1.0 / csqrt(2.0);
    for (int m = -L; m <= L; ++m) {
        double sgn = (m & 1) ? -1.0 : 1.0;
        if (m < 0) {
            R.r[(L - m) * D + (L + m)] = { 0.0, isq2 * sgn };
            R.r[(L + m) * D + (L + m)] = { 0.0, -isq2 };
        } else if (m == 0) {
            R.r[L * D + L] = { 1.0, 0.0 };
        } else {
            R.r[(L - m) * D + (L + m)] = { isq2, 0.0 };
            R.r[(L + m) * D + (L + m)] = { isq2 * sgn, 0.0 };
        }
    }
    return R;
}

struct Blk { double v[225]; };

constexpr Blk cg_real(int l1, int l2, int L) {
    Blk out{};
    int D1 = 2 * l1 + 1, D2 = 2 * l2 + 1, DL = 2 * L + 1;
    double ccg[225] = {};
    for (int m1 = -l1; m1 <= l1; ++m1)
        for (int m2 = -l2; m2 <= l2; ++m2) {
            int M = m1 + m2;
            if (M >= -L && M <= L)
                ccg[((m1 + l1) * D2 + (m2 + l2)) * DL + (M + L)] = cg_coeff(l1, m1, l2, m2, L, M);
        }
    R2C R1 = real2complex(l1);
    R2C R2 = real2complex(l2);
    R2C RL = real2complex(L);
    bool even = ((l1 + l2 + L) % 2) == 0;
    for (int a = 0; a < D1; ++a)
        for (int b = 0; b < D2; ++b) {
            C2 tmp[9] = {};
            for (int M = 0; M < DL; ++M) {
                C2 s = { 0.0, 0.0 };
                for (int m = 0; m < D1; ++m)
                    for (int nn = 0; nn < D2; ++nn) {
                        double cc = ccg[(m * D2 + nn) * DL + M];
                        if (cc != 0.0)
                            s = cadd(s, cscale(cmul(R1.r[m * D1 + a], R2.r[nn * D2 + b]), cc));
                    }
                tmp[M] = s;
            }
            for (int k = 0; k < DL; ++k) {
                C2 s = { 0.0, 0.0 };
                for (int M = 0; M < DL; ++M)
                    s = cadd(s, cmul(tmp[M], conjc(RL.r[M * DL + k])));
                out.v[(a * D2 + b) * DL + k] = even ? s.re : s.im;
            }
        }
    return out;
}

constexpr Blk B2_0 = cg_real(1, 1, 0);
constexpr Blk B2_1 = cg_real(1, 1, 1);
constexpr Blk B2_2 = cg_real(1, 1, 2);
constexpr Blk B4_0 = cg_real(2, 2, 0);
constexpr Blk B4_1 = cg_real(2, 2, 1);
constexpr Blk B4_2 = cg_real(2, 2, 2);
constexpr Blk B4_3 = cg_real(2, 2, 3);
constexpr Blk B4_4 = cg_real(2, 2, 4);

struct U9T  { float u[81];  };
struct U25T { float u[625]; };

constexpr U9T build_U9() {
    U9T U{};
    const Blk* bl[3] = { &B2_0, &B2_1, &B2_2 };
    int off = 0;
    for (int L = 0; L <= 2; ++L) {
        int DL = 2 * L + 1;
        for (int a = 0; a < 3; ++a)
            for (int b = 0; b < 3; ++b)
                for (int k = 0; k < DL; ++k)
                    U.u[(a * 3 + b) * 9 + (off + k)] = (float)bl[L]->v[(a * 3 + b) * DL + k];
        off += DL;
    }
    return U;
}

constexpr U25T build_U25() {
    U25T U{};
    const Blk* bl[5] = { &B4_0, &B4_1, &B4_2, &B4_3, &B4_4 };
    int off = 0;
    for (int L = 0; L <= 4; ++L) {
        int DL = 2 * L + 1;
        for (int a = 0; a < 5; ++a)
            for (int b = 0; b < 5; ++b)
                for (int k = 0; k < DL; ++k)
                    U.u[(a * 5 + b) * 25 + (off + k)] = (float)bl[L]->v[(a * 5 + b) * DL + k];
        off += DL;
    }
    return U;
}

constexpr U9T  U9c  = build_U9();
constexpr U25T U25c = build_U25();

} // namespace cgc

// ================= register-prefetch fused kernel =================
// One thread = (sample n, channel c). NO LDS, NO barriers.
// All 60 input loads are issued in one block at the top (max memory-level
// parallelism: ~15 KB outstanding per wave); compute consumes values as
// s_waitcnt releases them, band by band; each band's outputs store (NT)
// as soon as computed.

__global__ __launch_bounds__(256) void tp_reg_kernel(
    const float* __restrict__ f1_0, const float* __restrict__ f1_1,
    const float* __restrict__ f1_2, const float* __restrict__ f1_3,
    const float* __restrict__ f2_0, const float* __restrict__ f2_1,
    const float* __restrict__ f2_2, const float* __restrict__ f2_3,
    float* __restrict__ out)
{
    using namespace cgc;
    const int t = blockIdx.x * 256 + threadIdx.x;
    const int n = t >> 6, c = t & 63;
    const int r0 = n * 256, r1 = n * 576, r2 = n * 640, r3 = n * 448;

    // ---------------- load phase: all 60 inputs ----------------
    // band 0 (ch 192+c)
    float z1 = f1_0[r0 + 192 + c];
    float z2 = f2_0[r0 + 192 + c];
    // band 1 (ch 128+c)
    float a1[4], a2[4];
    a1[0] = f1_0[r0 + 128 + c];
    a2[0] = f2_0[r0 + 128 + c];
#pragma unroll
    for (int m = 0; m < 3; ++m) {
        a1[1 + m] = f1_1[r1 + m * 192 + 128 + c];
        a2[1 + m] = f2_1[r1 + m * 192 + 128 + c];
    }
    // band 2 (ch 64+c)
    float b1v[9], b2v[9];
    b1v[0] = f1_0[r0 + 64 + c];
    b2v[0] = f2_0[r0 + 64 + c];
#pragma unroll
    for (int m = 0; m < 3; ++m) {
        b1v[1 + m] = f1_1[r1 + m * 192 + 64 + c];
        b2v[1 + m] = f2_1[r1 + m * 192 + 64 + c];
    }
#pragma unroll
    for (int m = 0; m < 5; ++m) {
        b1v[4 + m] = f1_2[r2 + m * 128 + 64 + c];
        b2v[4 + m] = f2_2[r2 + m * 128 + 64 + c];
    }
    // band 3 (ch c)
    float c1v[16], c2v[16];
    c1v[0] = f1_0[r0 + c];
    c2v[0] = f2_0[r0 + c];
#pragma unroll
    for (int m = 0; m < 3; ++m) {
        c1v[1 + m] = f1_1[r1 + m * 192 + c];
        c2v[1 + m] = f2_1[r1 + m * 192 + c];
    }
#pragma unroll
    for (int m = 0; m < 5; ++m) {
        c1v[4 + m] = f1_2[r2 + m * 128 + c];
        c2v[4 + m] = f2_2[r2 + m * 128 + c];
    }
#pragma unroll
    for (int m = 0; m < 7; ++m) {
        c1v[9 + m] = f1_3[r3 + m * 64 + c];
        c2v[9 + m] = f2_3[r3 + m * 64 + c];
    }

    // ---------------- band 0 ----------------
    __builtin_nontemporal_store(z1 * z2, &out[r0 + c]);

    // ---------------- band 1 (pl=2, 4/9 inputs, outputs L=0,1) ----------------
    {
        float A[9], B[9];
#pragma unroll
        for (int M = 0; M < 9; ++M) {
            float sa = 0.f, sb = 0.f;
#pragma unroll
            for (int N = 0; N < 4; ++N)
                if (U9c.u[M * 9 + N] != 0.0f) {
                    sa += U9c.u[M * 9 + N] * a1[N];
                    sb += U9c.u[M * 9 + N] * a2[N];
                }
            A[M] = sa; B[M] = sb;
        }
        float C[9];
#pragma unroll
        for (int i = 0; i < 3; ++i)
#pragma unroll
            for (int k = 0; k < 3; ++k) {
                float sC = 0.f;
#pragma unroll
                for (int j = 0; j < 3; ++j) sC += A[i * 3 + j] * B[j * 3 + k];
                C[i * 3 + k] = sC;
            }
        float y[4];
#pragma unroll
        for (int M = 0; M < 4; ++M) {
            float sY = 0.f;
#pragma unroll
            for (int N = 0; N < 9; ++N)
                if (U9c.u[N * 9 + M] != 0.0f) sY += U9c.u[N * 9 + M] * C[N];
            y[M] = sY;
        }
        __builtin_nontemporal_store(y[0], &out[r0 + 64 + c]);
#pragma unroll
        for (int m = 0; m < 3; ++m)
            __builtin_nontemporal_store(y[1 + m], &out[OUT1_BASE + r1 + m * 192 + c]);
    }

    // ---------------- band 2 (pl=2, 9 inputs, outputs L=0..2) ----------------
    {
        float A[9], B[9];
#pragma unroll
        for (int M = 0; M < 9; ++M) {
            float sa = 0.f, sb = 0.f;
#pragma unroll
            for (int N = 0; N < 9; ++N)
                if (U9c.u[M * 9 + N] != 0.0f) {
                    sa += U9c.u[M * 9 + N] * b1v[N];
                    sb += U9c.u[M * 9 + N] * b2v[N];
                }
            A[M] = sa; B[M] = sb;
        }
        float C[9];
#pragma unroll
        for (int i = 0; i < 3; ++i)
#pragma unroll
            for (int k = 0; k < 3; ++k) {
                float sC = 0.f;
#pragma unroll
                for (int j = 0; j < 3; ++j) sC += A[i * 3 + j] * B[j * 3 + k];
                C[i * 3 + k] = sC;
            }
        float y[9];
#pragma unroll
        for (int M = 0; M < 9; ++M) {
            float sY = 0.f;
#pragma unroll
            for (int N = 0; N < 9; ++N)
                if (U9c.u[N * 9 + M] != 0.0f) sY += U9c.u[N * 9 + M] * C[N];
            y[M] = sY;
        }
        __builtin_nontemporal_store(y[0], &out[r0 + 128 + c]);
#pragma unroll
        for (int m = 0; m < 3; ++m)
            __builtin_nontemporal_store(y[1 + m], &out[OUT1_BASE + r1 + m * 192 + 64 + c]);
#pragma unroll
        for (int m = 0; m < 5; ++m)
            __builtin_nontemporal_store(y[4 + m], &out[OUT2_BASE + r2 + m * 128 + c]);
    }

    // ---------------- band 3 (pl=4, 16/25 inputs, outputs L=0..3) ----------------
    {
        float A[25], B[25];
#pragma unroll
        for (int M = 0; M < 25; ++M) {
            float sa = 0.f, sb = 0.f;
#pragma unroll
            for (int N = 0; N < 16; ++N)
                if (U25c.u[M * 25 + N] != 0.0f) {
                    sa += U25c.u[M * 25 + N] * c1v[N];
                    sb += U25c.u[M * 25 + N] * c2v[N];
                }
            A[M] = sa; B[M] = sb;
        }
        float C[25];
#pragma unroll
        for (int i = 0; i < 5; ++i)
#pragma unroll
            for (int k = 0; k < 5; ++k) {
                float sC = 0.f;
#pragma unroll
                for (int j = 0; j < 5; ++j) sC += A[i * 5 + j] * B[j * 5 + k];
                C[i * 5 + k] = sC;
            }
        float y[16];
#pragma unroll
        for (int M = 0; M < 16; ++M) {
            float sY = 0.f;
#pragma unroll
            for (int N = 0; N < 25; ++N)
                if (U25c.u[N * 25 + M] != 0.0f) sY += U25c.u[N * 25 + M] * C[N];
            y[M] = sY;
        }
        __builtin_nontemporal_store(y[0], &out[r0 + 192 + c]);
#pragma unroll
        for (int m = 0; m < 3; ++m)
            __builtin_nontemporal_store(y[1 + m], &out[OUT1_BASE + r1 + m * 192 + 128 + c]);
#pragma unroll
        for (int m = 0; m < 5; ++m)
            __builtin_nontemporal_store(y[4 + m], &out[OUT2_BASE + r2 + m * 128 + 64 + c]);
#pragma unroll
        for (int m = 0; m < 7; ++m)
            __builtin_nontemporal_store(y[9 + m], &out[OUT3_BASE + r3 + m * 64 + c]);
    }
}

// ---------------- launch ----------------
extern "C" void kernel_launch(void* const* d_in, const int* in_sizes, int n_in,
                              void* d_out, int out_size, void* d_ws, size_t ws_size,
                              hipStream_t stream)
{
    const float* f1_0 = (const float*)d_in[0];
    const float* f1_1 = (const float*)d_in[1];
    const float* f1_2 = (const float*)d_in[2];
    const float* f1_3 = (const float*)d_in[3];
    const float* f2_0 = (const float*)d_in[4];
    const float* f2_1 = (const float*)d_in[5];
    const float* f2_2 = (const float*)d_in[6];
    const float* f2_3 = (const float*)d_in[7];
    float* out = (float*)d_out;

    dim3 blk(256);
    dim3 grid(NS / 4);   // 4 samples/block, lane = channel

    tp_reg_kernel<<<grid, blk, 0, stream>>>(f1_0, f1_1, f1_2, f1_3,
                                            f2_0, f2_1, f2_2, f2_3, out);
}

// Round 5
// 138.565 us; speedup vs baseline: 1.0625x; 1.0001x over previous
//
#include <hip/hip_runtime.h>

// ---------------- problem constants ----------------
#define NS 32768
// output flat offsets (fp32 elements)
#define OUT1_BASE (NS * 256)                 // 8388608
#define OUT2_BASE (OUT1_BASE + NS * 576)     // 27262976
#define OUT3_BASE (OUT2_BASE + NS * 640)     // 48234496

typedef float f2 __attribute__((ext_vector_type(2)));

// ================= compile-time U construction =================
namespace cgc {

constexpr double hfact(int n) { double r = 1.0; for (int i = 2; i <= n; ++i) r *= (double)i; return r; }

constexpr double csqrt(double a) {
    if (a <= 0.0) return 0.0;
    double x = a > 1.0 ? a : 1.0;
    for (int i = 0; i < 64; ++i) x = 0.5 * (x + a / x);
    return x;
}

constexpr double cg_coeff(int j1, int m1, int j2, int m2, int J, int M) {
    if (m1 + m2 != M) return 0.0;
    double pref = (2.0 * J + 1.0) * hfact(j1 + j2 - J) * hfact(j1 - j2 + J)
                * hfact(-j1 + j2 + J) / hfact(j1 + j2 + J + 1);
    pref *= hfact(J + M) * hfact(J - M) * hfact(j1 - m1) * hfact(j1 + m1)
          * hfact(j2 - m2) * hfact(j2 + m2);
    int kmin = 0;
    if (j2 - J - m1 > kmin) kmin = j2 - J - m1;
    if (j1 + m2 - J > kmin) kmin = j1 + m2 - J;
    int kmax = j1 + j2 - J;
    if (j1 - m1 < kmax) kmax = j1 - m1;
    if (j2 + m2 < kmax) kmax = j2 + m2;
    double s = 0.0;
    for (int k = kmin; k <= kmax; ++k) {
        double d = hfact(k) * hfact(j1 + j2 - J - k) * hfact(j1 - m1 - k)
                 * hfact(j2 + m2 - k) * hfact(J - j2 + m1 + k) * hfact(J - j1 - m2 + k);
        s += ((k & 1) ? -1.0 : 1.0) / d;
    }
    return csqrt(pref) * s;
}

struct C2 { double re; double im; };
constexpr C2 cmul(C2 a, C2 b) { return { a.re * b.re - a.im * b.im, a.re * b.im + a.im * b.re }; }
constexpr C2 cadd(C2 a, C2 b) { return { a.re + b.re, a.im + b.im }; }
constexpr C2 cscale(C2 a, double s) { return { a.re * s, a.im * s }; }
constexpr C2 conjc(C2 a) { return { a.re, -a.im }; }

struct R2C { C2 r[81]; };

constexpr R2C real2complex(int L) {
    R2C R{};
    int D = 2 * L + 1;
    double isq2 = 1.0 / csqrt(2.0);
    for (int m = -L; m <= L; ++m) {
        double sgn = (m & 1) ? -1.0 : 1.0;
        if (m < 0) {
            R.r[(L - m) * D + (L + m)] = { 0.0, isq2 * sgn };
            R.r[(L + m) * D + (L + m)] = { 0.0, -isq2 };
        } else if (m == 0) {
            R.r[L * D + L] = { 1.0, 0.0 };
        } else {
            R.r[(L - m) * D + (L + m)] = { isq2, 0.0 };
            R.r[(L + m) * D + (L + m)] = { isq2 * sgn, 0.0 };
        }
    }
    return R;
}

struct Blk { double v[225]; };

constexpr Blk cg_real(int l1, int l2, int L) {
    Blk out{};
    int D1 = 2 * l1 + 1, D2 = 2 * l2 + 1, DL = 2 * L + 1;
    double ccg[225] = {};
    for (int m1 = -l1; m1 <= l1; ++m1)
        for (int m2 = -l2; m2 <= l2; ++m2) {
            int M = m1 + m2;
            if (M >= -L && M <= L)
                ccg[((m1 + l1) * D2 + (m2 + l2)) * DL + (M + L)] = cg_coeff(l1, m1, l2, m2, L, M);
        }
    R2C R1 = real2complex(l1);
    R2C R2 = real2complex(l2);
    R2C RL = real2complex(L);
    bool even = ((l1 + l2 + L) % 2) == 0;
    for (int a = 0; a < D1; ++a)
        for (int b = 0; b < D2; ++b) {
            C2 tmp[9] = {};
            for (int M = 0; M < DL; ++M) {
                C2 s = { 0.0, 0.0 };
                for (int m = 0; m < D1; ++m)
                    for (int nn = 0; nn < D2; ++nn) {
                        double cc = ccg[(m * D2 + nn) * DL + M];
                        if (cc != 0.0)
                            s = cadd(s, cscale(cmul(R1.r[m * D1 + a], R2.r[nn * D2 + b]), cc));
                    }
                tmp[M] = s;
            }
            for (int k = 0; k < DL; ++k) {
                C2 s = { 0.0, 0.0 };
                for (int M = 0; M < DL; ++M)
                    s = cadd(s, cmul(tmp[M], conjc(RL.r[M * DL + k])));
                out.v[(a * D2 + b) * DL + k] = even ? s.re : s.im;
            }
        }
    return out;
}

constexpr Blk B2_0 = cg_real(1, 1, 0);
constexpr Blk B2_1 = cg_real(1, 1, 1);
constexpr Blk B2_2 = cg_real(1, 1, 2);
constexpr Blk B4_0 = cg_real(2, 2, 0);
constexpr Blk B4_1 = cg_real(2, 2, 1);
constexpr Blk B4_2 = cg_real(2, 2, 2);
constexpr Blk B4_3 = cg_real(2, 2, 3);
constexpr Blk B4_4 = cg_real(2, 2, 4);

struct U9T  { float u[81];  };
struct U25T { float u[625]; };

constexpr U9T build_U9() {
    U9T U{};
    const Blk* bl[3] = { &B2_0, &B2_1, &B2_2 };
    int off = 0;
    for (int L = 0; L <= 2; ++L) {
        int DL = 2 * L + 1;
        for (int a = 0; a < 3; ++a)
            for (int b = 0; b < 3; ++b)
                for (int k = 0; k < DL; ++k)
                    U.u[(a * 3 + b) * 9 + (off + k)] = (float)bl[L]->v[(a * 3 + b) * DL + k];
        off += DL;
    }
    return U;
}

constexpr U25T build_U25() {
    U25T U{};
    const Blk* bl[5] = { &B4_0, &B4_1, &B4_2, &B4_3, &B4_4 };
    int off = 0;
    for (int L = 0; L <= 4; ++L) {
        int DL = 2 * L + 1;
        for (int a = 0; a < 5; ++a)
            for (int b = 0; b < 5; ++b)
                for (int k = 0; k < DL; ++k)
                    U.u[(a * 5 + b) * 25 + (off + k)] = (float)bl[L]->v[(a * 5 + b) * DL + k];
        off += DL;
    }
    return U;
}

constexpr U9T  U9c  = build_U9();
constexpr U25T U25c = build_U25();

} // namespace cgc

// ================= float2 fused kernel =================
// One thread = (sample n, channel pair cp): channels 2cp, 2cp+1.
// Wave = 2 samples x 32 pairs; every global access is 8 B/lane, 512 B/wave-instr.
// Whole compute pipeline is float2 -> packed v_pk_fma_f32 + 2-channel ILP.

__global__ __launch_bounds__(256) void tp_f2_kernel(
    const float* __restrict__ f1_0, const float* __restrict__ f1_1,
    const float* __restrict__ f1_2, const float* __restrict__ f1_3,
    const float* __restrict__ f2_0, const float* __restrict__ f2_1,
    const float* __restrict__ f2_2, const float* __restrict__ f2_3,
    float* __restrict__ out)
{
    using namespace cgc;
    const int t = blockIdx.x * 256 + threadIdx.x;
    const int n = t >> 5;          // sample
    const int cc = (t & 31) * 2;   // channel (even)
    const int r0 = n * 256, r1 = n * 576, r2 = n * 640, r3 = n * 448;

#define LD2(p, i) (*(const f2*)((p) + (i)))
#define ST2(v, p, i) __builtin_nontemporal_store((v), (f2*)((p) + (i)))

    // ---------------- band 0 (ch 192:256) ----------------
    {
        f2 z1 = LD2(f1_0, r0 + 192 + cc);
        f2 z2 = LD2(f2_0, r0 + 192 + cc);
        ST2(z1 * z2, out, r0 + cc);
    }

    // ---------------- band 1 (pl=2, ch 128:192, 4/9 inputs, outputs L=0,1) ----------------
    {
        f2 x1[4], x2[4];
        x1[0] = LD2(f1_0, r0 + 128 + cc);
        x2[0] = LD2(f2_0, r0 + 128 + cc);
#pragma unroll
        for (int m = 0; m < 3; ++m) {
            x1[1 + m] = LD2(f1_1, r1 + m * 192 + 128 + cc);
            x2[1 + m] = LD2(f2_1, r1 + m * 192 + 128 + cc);
        }
        f2 A[9], B[9];
#pragma unroll
        for (int M = 0; M < 9; ++M) {
            f2 sa = { 0.f, 0.f }, sb = { 0.f, 0.f };
#pragma unroll
            for (int N = 0; N < 4; ++N)
                if (U9c.u[M * 9 + N] != 0.0f) {
                    sa += U9c.u[M * 9 + N] * x1[N];
                    sb += U9c.u[M * 9 + N] * x2[N];
                }
            A[M] = sa; B[M] = sb;
        }
        f2 C[9];
#pragma unroll
        for (int i = 0; i < 3; ++i)
#pragma unroll
            for (int k = 0; k < 3; ++k) {
                f2 sC = { 0.f, 0.f };
#pragma unroll
                for (int j = 0; j < 3; ++j) sC += A[i * 3 + j] * B[j * 3 + k];
                C[i * 3 + k] = sC;
            }
        f2 y[4];
#pragma unroll
        for (int M = 0; M < 4; ++M) {
            f2 sY = { 0.f, 0.f };
#pragma unroll
            for (int N = 0; N < 9; ++N)
                if (U9c.u[N * 9 + M] != 0.0f) sY += U9c.u[N * 9 + M] * C[N];
            y[M] = sY;
        }
        ST2(y[0], out, r0 + 64 + cc);
#pragma unroll
        for (int m = 0; m < 3; ++m)
            ST2(y[1 + m], out, OUT1_BASE + r1 + m * 192 + cc);
    }

    // ---------------- band 2 (pl=2, ch 64:128, 9 inputs, outputs L=0..2) ----------------
    {
        f2 x1[9], x2[9];
        x1[0] = LD2(f1_0, r0 + 64 + cc);
        x2[0] = LD2(f2_0, r0 + 64 + cc);
#pragma unroll
        for (int m = 0; m < 3; ++m) {
            x1[1 + m] = LD2(f1_1, r1 + m * 192 + 64 + cc);
            x2[1 + m] = LD2(f2_1, r1 + m * 192 + 64 + cc);
        }
#pragma unroll
        for (int m = 0; m < 5; ++m) {
            x1[4 + m] = LD2(f1_2, r2 + m * 128 + 64 + cc);
            x2[4 + m] = LD2(f2_2, r2 + m * 128 + 64 + cc);
        }
        f2 A[9], B[9];
#pragma unroll
        for (int M = 0; M < 9; ++M) {
            f2 sa = { 0.f, 0.f }, sb = { 0.f, 0.f };
#pragma unroll
            for (int N = 0; N < 9; ++N)
                if (U9c.u[M * 9 + N] != 0.0f) {
                    sa += U9c.u[M * 9 + N] * x1[N];
                    sb += U9c.u[M * 9 + N] * x2[N];
                }
            A[M] = sa; B[M] = sb;
        }
        f2 C[9];
#pragma unroll
        for (int i = 0; i < 3; ++i)
#pragma unroll
            for (int k = 0; k < 3; ++k) {
                f2 sC = { 0.f, 0.f };
#pragma unroll
                for (int j = 0; j < 3; ++j) sC += A[i * 3 + j] * B[j * 3 + k];
                C[i * 3 + k] = sC;
            }
        f2 y[9];
#pragma unroll
        for (int M = 0; M < 9; ++M) {
            f2 sY = { 0.f, 0.f };
#pragma unroll
            for (int N = 0; N < 9; ++N)
                if (U9c.u[N * 9 + M] != 0.0f) sY += U9c.u[N * 9 + M] * C[N];
            y[M] = sY;
        }
        ST2(y[0], out, r0 + 128 + cc);
#pragma unroll
        for (int m = 0; m < 3; ++m)
            ST2(y[1 + m], out, OUT1_BASE + r1 + m * 192 + 64 + cc);
#pragma unroll
        for (int m = 0; m < 5; ++m)
            ST2(y[4 + m], out, OUT2_BASE + r2 + m * 128 + cc);
    }

    // ---------------- band 3 (pl=4, ch 0:64, 16/25 inputs, outputs L=0..3) ----------------
    {
        f2 x1[16], x2[16];
        x1[0] = LD2(f1_0, r0 + cc);
        x2[0] = LD2(f2_0, r0 + cc);
#pragma unroll
        for (int m = 0; m < 3; ++m) {
            x1[1 + m] = LD2(f1_1, r1 + m * 192 + cc);
            x2[1 + m] = LD2(f2_1, r1 + m * 192 + cc);
        }
#pragma unroll
        for (int m = 0; m < 5; ++m) {
            x1[4 + m] = LD2(f1_2, r2 + m * 128 + cc);
            x2[4 + m] = LD2(f2_2, r2 + m * 128 + cc);
        }
#pragma unroll
        for (int m = 0; m < 7; ++m) {
            x1[9 + m] = LD2(f1_3, r3 + m * 64 + cc);
            x2[9 + m] = LD2(f2_3, r3 + m * 64 + cc);
        }
        f2 A[25], B[25];
#pragma unroll
        for (int M = 0; M < 25; ++M) {
            f2 sa = { 0.f, 0.f }, sb = { 0.f, 0.f };
#pragma unroll
            for (int N = 0; N < 16; ++N)
                if (U25c.u[M * 25 + N] != 0.0f) {
                    sa += U25c.u[M * 25 + N] * x1[N];
                    sb += U25c.u[M * 25 + N] * x2[N];
                }
            A[M] = sa; B[M] = sb;
        }
        f2 C[25];
#pragma unroll
        for (int i = 0; i < 5; ++i)
#pragma unroll
            for (int k = 0; k < 5; ++k) {
                f2 sC = { 0.f, 0.f };
#pragma unroll
                for (int j = 0; j < 5; ++j) sC += A[i * 5 + j] * B[j * 5 + k];
                C[i * 5 + k] = sC;
            }
        f2 y[16];
#pragma unroll
        for (int M = 0; M < 16; ++M) {
            f2 sY = { 0.f, 0.f };
#pragma unroll
            for (int N = 0; N < 25; ++N)
                if (U25c.u[N * 25 + M] != 0.0f) sY += U25c.u[N * 25 + M] * C[N];
            y[M] = sY;
        }
        ST2(y[0], out, r0 + 192 + cc);
#pragma unroll
        for (int m = 0; m < 3; ++m)
            ST2(y[1 + m], out, OUT1_BASE + r1 + m * 192 + 128 + cc);
#pragma unroll
        for (int m = 0; m < 5; ++m)
            ST2(y[4 + m], out, OUT2_BASE + r2 + m * 128 + 64 + cc);
#pragma unroll
        for (int m = 0; m < 7; ++m)
            ST2(y[9 + m], out, OUT3_BASE + r3 + m * 64 + cc);
    }
#undef LD2
#undef ST2
}

// ---------------- launch ----------------
extern "C" void kernel_launch(void* const* d_in, const int* in_sizes, int n_in,
                              void* d_out, int out_size, void* d_ws, size_t ws_size,
                              hipStream_t stream)
{
    const float* f1_0 = (const float*)d_in[0];
    const float* f1_1 = (const float*)d_in[1];
    const float* f1_2 = (const float*)d_in[2];
    const float* f1_3 = (const float*)d_in[3];
    const float* f2_0 = (const float*)d_in[4];
    const float* f2_1 = (const float*)d_in[5];
    const float* f2_2 = (const float*)d_in[6];
    const float* f2_3 = (const float*)d_in[7];
    float* out = (float*)d_out;

    dim3 blk(256);
    dim3 grid(NS / 8);   // 8 samples per block (2 per wave), 32 channel-pairs

    tp_f2_kernel<<<grid, blk, 0, stream>>>(f1_0, f1_1, f1_2, f1_3,
                                           f2_0, f2_1, f2_2, f2_3, out);
}

// Round 6
// 137.514 us; speedup vs baseline: 1.0706x; 1.0076x over previous
//
#include <hip/hip_runtime.h>

// ---------------- problem constants ----------------
#define NS 32768
// output flat offsets (fp32 elements)
#define OUT1_BASE (NS * 256)                 // 8388608
#define OUT2_BASE (OUT1_BASE + NS * 576)     // 27262976
#define OUT3_BASE (OUT2_BASE + NS * 640)     // 48234496

typedef float f2 __attribute__((ext_vector_type(2)));

// ================= compile-time U construction =================
namespace cgc {

constexpr double hfact(int n) { double r = 1.0; for (int i = 2; i <= n; ++i) r *= (double)i; return r; }

constexpr double csqrt(double a) {
    if (a <= 0.0) return 0.0;
    double x = a > 1.0 ? a : 1.0;
    for (int i = 0; i < 64; ++i) x = 0.5 * (x + a / x);
    return x;
}

constexpr double cg_coeff(int j1, int m1, int j2, int m2, int J, int M) {
    if (m1 + m2 != M) return 0.0;
    double pref = (2.0 * J + 1.0) * hfact(j1 + j2 - J) * hfact(j1 - j2 + J)
                * hfact(-j1 + j2 + J) / hfact(j1 + j2 + J + 1);
    pref *= hfact(J + M) * hfact(J - M) * hfact(j1 - m1) * hfact(j1 + m1)
          * hfact(j2 - m2) * hfact(j2 + m2);
    int kmin = 0;
    if (j2 - J - m1 > kmin) kmin = j2 - J - m1;
    if (j1 + m2 - J > kmin) kmin = j1 + m2 - J;
    int kmax = j1 + j2 - J;
    if (j1 - m1 < kmax) kmax = j1 - m1;
    if (j2 + m2 < kmax) kmax = j2 + m2;
    double s = 0.0;
    for (int k = kmin; k <= kmax; ++k) {
        double d = hfact(k) * hfact(j1 + j2 - J - k) * hfact(j1 - m1 - k)
                 * hfact(j2 + m2 - k) * hfact(J - j2 + m1 + k) * hfact(J - j1 - m2 + k);
        s += ((k & 1) ? -1.0 : 1.0) / d;
    }
    return csqrt(pref) * s;
}

struct C2 { double re; double im; };
constexpr C2 cmul(C2 a, C2 b) { return { a.re * b.re - a.im * b.im, a.re * b.im + a.im * b.re }; }
constexpr C2 cadd(C2 a, C2 b) { return { a.re + b.re, a.im + b.im }; }
constexpr C2 cscale(C2 a, double s) { return { a.re * s, a.im * s }; }
constexpr C2 conjc(C2 a) { return { a.re, -a.im }; }

struct R2C { C2 r[81]; };

constexpr R2C real2complex(int L) {
    R2C R{};
    int D = 2 * L + 1;
    double isq2 = 1.0 / csqrt(2.0);
    for (int m = -L; m <= L; ++m) {
        double sgn = (m & 1) ? -1.0 : 1.0;
        if (m < 0) {
            R.r[(L - m) * D + (L + m)] = { 0.0, isq2 * sgn };
            R.r[(L + m) * D + (L + m)] = { 0.0, -isq2 };
        } else if (m == 0) {
            R.r[L * D + L] = { 1.0, 0.0 };
        } else {
            R.r[(L - m) * D + (L + m)] = { isq2, 0.0 };
            R.r[(L + m) * D + (L + m)] = { isq2 * sgn, 0.0 };
        }
    }
    return R;
}

struct Blk { double v[225]; };

constexpr Blk cg_real(int l1, int l2, int L) {
    Blk out{};
    int D1 = 2 * l1 + 1, D2 = 2 * l2 + 1, DL = 2 * L + 1;
    double ccg[225] = {};
    for (int m1 = -l1; m1 <= l1; ++m1)
        for (int m2 = -l2; m2 <= l2; ++m2) {
            int M = m1 + m2;
            if (M >= -L && M <= L)
                ccg[((m1 + l1) * D2 + (m2 + l2)) * DL + (M + L)] = cg_coeff(l1, m1, l2, m2, L, M);
        }
    R2C R1 = real2complex(l1);
    R2C R2 = real2complex(l2);
    R2C RL = real2complex(L);
    bool even = ((l1 + l2 + L) % 2) == 0;
    for (int a = 0; a < D1; ++a)
        for (int b = 0; b < D2; ++b) {
            C2 tmp[9] = {};
            for (int M = 0; M < DL; ++M) {
                C2 s = { 0.0, 0.0 };
                for (int m = 0; m < D1; ++m)
                    for (int nn = 0; nn < D2; ++nn) {
                        double cc = ccg[(m * D2 + nn) * DL + M];
                        if (cc != 0.0)
                            s = cadd(s, cscale(cmul(R1.r[m * D1 + a], R2.r[nn * D2 + b]), cc));
                    }
                tmp[M] = s;
            }
            for (int k = 0; k < DL; ++k) {
                C2 s = { 0.0, 0.0 };
                for (int M = 0; M < DL; ++M)
                    s = cadd(s, cmul(tmp[M], conjc(RL.r[M * DL + k])));
                out.v[(a * D2 + b) * DL + k] = even ? s.re : s.im;
            }
        }
    return out;
}

constexpr Blk B2_0 = cg_real(1, 1, 0);
constexpr Blk B2_1 = cg_real(1, 1, 1);
constexpr Blk B2_2 = cg_real(1, 1, 2);
constexpr Blk B4_0 = cg_real(2, 2, 0);
constexpr Blk B4_1 = cg_real(2, 2, 1);
constexpr Blk B4_2 = cg_real(2, 2, 2);
constexpr Blk B4_3 = cg_real(2, 2, 3);
constexpr Blk B4_4 = cg_real(2, 2, 4);

struct U9T  { float u[81];  };
struct U25T { float u[625]; };

constexpr U9T build_U9() {
    U9T U{};
    const Blk* bl[3] = { &B2_0, &B2_1, &B2_2 };
    int off = 0;
    for (int L = 0; L <= 2; ++L) {
        int DL = 2 * L + 1;
        for (int a = 0; a < 3; ++a)
            for (int b = 0; b < 3; ++b)
                for (int k = 0; k < DL; ++k)
                    U.u[(a * 3 + b) * 9 + (off + k)] = (float)bl[L]->v[(a * 3 + b) * DL + k];
        off += DL;
    }
    return U;
}

constexpr U25T build_U25() {
    U25T U{};
    const Blk* bl[5] = { &B4_0, &B4_1, &B4_2, &B4_3, &B4_4 };
    int off = 0;
    for (int L = 0; L <= 4; ++L) {
        int DL = 2 * L + 1;
        for (int a = 0; a < 5; ++a)
            for (int b = 0; b < 5; ++b)
                for (int k = 0; k < DL; ++k)
                    U.u[(a * 5 + b) * 25 + (off + k)] = (float)bl[L]->v[(a * 5 + b) * DL + k];
        off += DL;
    }
    return U;
}

constexpr U9T  U9c  = build_U9();
constexpr U25T U25c = build_U25();

} // namespace cgc

// ================= float2 + pinned-prefetch fused kernel =================
// One thread = (sample n, channel pair). ALL 30 f2 loads are issued in a
// single block, then __builtin_amdgcn_sched_barrier(0) forbids the compiler
// from sinking any of them into the compute — 15 KB outstanding per wave,
// saturating HBM even at ~3 waves/SIMD.

__global__ __launch_bounds__(256) void tp_f2p_kernel(
    const float* __restrict__ f1_0, const float* __restrict__ f1_1,
    const float* __restrict__ f1_2, const float* __restrict__ f1_3,
    const float* __restrict__ f2_0, const float* __restrict__ f2_1,
    const float* __restrict__ f2_2, const float* __restrict__ f2_3,
    float* __restrict__ out)
{
    using namespace cgc;
    const int t = blockIdx.x * 256 + threadIdx.x;
    const int n = t >> 5;          // sample
    const int cc = (t & 31) * 2;   // channel (even)
    const int r0 = n * 256, r1 = n * 576, r2 = n * 640, r3 = n * 448;

#define LD2(p, i) (*(const f2*)((p) + (i)))
#define ST2(v, p, i) __builtin_nontemporal_store((v), (f2*)((p) + (i)))

    // ================ LOAD PHASE: all 30 f2 loads ================
    // band 0 (ch 192:256)
    f2 z1 = LD2(f1_0, r0 + 192 + cc);
    f2 z2 = LD2(f2_0, r0 + 192 + cc);
    // band 1 (ch 128:192): 4 of 9
    f2 a1[4], a2[4];
    a1[0] = LD2(f1_0, r0 + 128 + cc);
    a2[0] = LD2(f2_0, r0 + 128 + cc);
#pragma unroll
    for (int m = 0; m < 3; ++m) {
        a1[1 + m] = LD2(f1_1, r1 + m * 192 + 128 + cc);
        a2[1 + m] = LD2(f2_1, r1 + m * 192 + 128 + cc);
    }
    // band 2 (ch 64:128): all 9
    f2 b1[9], b2[9];
    b1[0] = LD2(f1_0, r0 + 64 + cc);
    b2[0] = LD2(f2_0, r0 + 64 + cc);
#pragma unroll
    for (int m = 0; m < 3; ++m) {
        b1[1 + m] = LD2(f1_1, r1 + m * 192 + 64 + cc);
        b2[1 + m] = LD2(f2_1, r1 + m * 192 + 64 + cc);
    }
#pragma unroll
    for (int m = 0; m < 5; ++m) {
        b1[4 + m] = LD2(f1_2, r2 + m * 128 + 64 + cc);
        b2[4 + m] = LD2(f2_2, r2 + m * 128 + 64 + cc);
    }
    // band 3 (ch 0:64): 16 of 25
    f2 c1[16], c2[16];
    c1[0] = LD2(f1_0, r0 + cc);
    c2[0] = LD2(f2_0, r0 + cc);
#pragma unroll
    for (int m = 0; m < 3; ++m) {
        c1[1 + m] = LD2(f1_1, r1 + m * 192 + cc);
        c2[1 + m] = LD2(f2_1, r1 + m * 192 + cc);
    }
#pragma unroll
    for (int m = 0; m < 5; ++m) {
        c1[4 + m] = LD2(f1_2, r2 + m * 128 + cc);
        c2[4 + m] = LD2(f2_2, r2 + m * 128 + cc);
    }
#pragma unroll
    for (int m = 0; m < 7; ++m) {
        c1[9 + m] = LD2(f1_3, r3 + m * 64 + cc);
        c2[9 + m] = LD2(f2_3, r3 + m * 64 + cc);
    }

    // pin: no load may be scheduled after this point, no compute before it
    __builtin_amdgcn_sched_barrier(0);

    // ================ COMPUTE PHASE ================
    // band 0
    ST2(z1 * z2, out, r0 + cc);

    // band 1 (outputs L=0,1)
    {
        f2 A[9], B[9];
#pragma unroll
        for (int M = 0; M < 9; ++M) {
            f2 sa = { 0.f, 0.f }, sb = { 0.f, 0.f };
#pragma unroll
            for (int N = 0; N < 4; ++N)
                if (U9c.u[M * 9 + N] != 0.0f) {
                    sa += U9c.u[M * 9 + N] * a1[N];
                    sb += U9c.u[M * 9 + N] * a2[N];
                }
            A[M] = sa; B[M] = sb;
        }
        f2 C[9];
#pragma unroll
        for (int i = 0; i < 3; ++i)
#pragma unroll
            for (int k = 0; k < 3; ++k) {
                f2 sC = { 0.f, 0.f };
#pragma unroll
                for (int j = 0; j < 3; ++j) sC += A[i * 3 + j] * B[j * 3 + k];
                C[i * 3 + k] = sC;
            }
        f2 y[4];
#pragma unroll
        for (int M = 0; M < 4; ++M) {
            f2 sY = { 0.f, 0.f };
#pragma unroll
            for (int N = 0; N < 9; ++N)
                if (U9c.u[N * 9 + M] != 0.0f) sY += U9c.u[N * 9 + M] * C[N];
            y[M] = sY;
        }
        ST2(y[0], out, r0 + 64 + cc);
#pragma unroll
        for (int m = 0; m < 3; ++m)
            ST2(y[1 + m], out, OUT1_BASE + r1 + m * 192 + cc);
    }

    // band 2 (outputs L=0..2)
    {
        f2 A[9], B[9];
#pragma unroll
        for (int M = 0; M < 9; ++M) {
            f2 sa = { 0.f, 0.f }, sb = { 0.f, 0.f };
#pragma unroll
            for (int N = 0; N < 9; ++N)
                if (U9c.u[M * 9 + N] != 0.0f) {
                    sa += U9c.u[M * 9 + N] * b1[N];
                    sb += U9c.u[M * 9 + N] * b2[N];
                }
            A[M] = sa; B[M] = sb;
        }
        f2 C[9];
#pragma unroll
        for (int i = 0; i < 3; ++i)
#pragma unroll
            for (int k = 0; k < 3; ++k) {
                f2 sC = { 0.f, 0.f };
#pragma unroll
                for (int j = 0; j < 3; ++j) sC += A[i * 3 + j] * B[j * 3 + k];
                C[i * 3 + k] = sC;
            }
        f2 y[9];
#pragma unroll
        for (int M = 0; M < 9; ++M) {
            f2 sY = { 0.f, 0.f };
#pragma unroll
            for (int N = 0; N < 9; ++N)
                if (U9c.u[N * 9 + M] != 0.0f) sY += U9c.u[N * 9 + M] * C[N];
            y[M] = sY;
        }
        ST2(y[0], out, r0 + 128 + cc);
#pragma unroll
        for (int m = 0; m < 3; ++m)
            ST2(y[1 + m], out, OUT1_BASE + r1 + m * 192 + 64 + cc);
#pragma unroll
        for (int m = 0; m < 5; ++m)
            ST2(y[4 + m], out, OUT2_BASE + r2 + m * 128 + cc);
    }

    // band 3 (outputs L=0..3)
    {
        f2 A[25], B[25];
#pragma unroll
        for (int M = 0; M < 25; ++M) {
            f2 sa = { 0.f, 0.f }, sb = { 0.f, 0.f };
#pragma unroll
            for (int N = 0; N < 16; ++N)
                if (U25c.u[M * 25 + N] != 0.0f) {
                    sa += U25c.u[M * 25 + N] * c1[N];
                    sb += U25c.u[M * 25 + N] * c2[N];
                }
            A[M] = sa; B[M] = sb;
        }
        f2 C[25];
#pragma unroll
        for (int i = 0; i < 5; ++i)
#pragma unroll
            for (int k = 0; k < 5; ++k) {
                f2 sC = { 0.f, 0.f };
#pragma unroll
                for (int j = 0; j < 5; ++j) sC += A[i * 5 + j] * B[j * 5 + k];
                C[i * 5 + k] = sC;
            }
        f2 y[16];
#pragma unroll
        for (int M = 0; M < 16; ++M) {
            f2 sY = { 0.f, 0.f };
#pragma unroll
            for (int N = 0; N < 25; ++N)
                if (U25c.u[N * 25 + M] != 0.0f) sY += U25c.u[N * 25 + M] * C[N];
            y[M] = sY;
        }
        ST2(y[0], out, r0 + 192 + cc);
#pragma unroll
        for (int m = 0; m < 3; ++m)
            ST2(y[1 + m], out, OUT1_BASE + r1 + m * 192 + 128 + cc);
#pragma unroll
        for (int m = 0; m < 5; ++m)
            ST2(y[4 + m], out, OUT2_BASE + r2 + m * 128 + 64 + cc);
#pragma unroll
        for (int m = 0; m < 7; ++m)
            ST2(y[9 + m], out, OUT3_BASE + r3 + m * 64 + cc);
    }
#undef LD2
#undef ST2
}

// ---------------- launch ----------------
extern "C" void kernel_launch(void* const* d_in, const int* in_sizes, int n_in,
                              void* d_out, int out_size, void* d_ws, size_t ws_size,
                              hipStream_t stream)
{
    const float* f1_0 = (const float*)d_in[0];
    const float* f1_1 = (const float*)d_in[1];
    const float* f1_2 = (const float*)d_in[2];
    const float* f1_3 = (const float*)d_in[3];
    const float* f2_0 = (const float*)d_in[4];
    const float* f2_1 = (const float*)d_in[5];
    const float* f2_2 = (const float*)d_in[6];
    const float* f2_3 = (const float*)d_in[7];
    float* out = (float*)d_out;

    dim3 blk(256);
    dim3 grid(NS / 8);   // 8 samples per block (2 per wave), 32 channel-pairs

    tp_f2p_kernel<<<grid, blk, 0, stream>>>(f1_0, f1_1, f1_2, f1_3,
                                            f2_0, f2_1, f2_2, f2_3, out);
}